// Round 1
// baseline (198.500 us; speedup 1.0000x reference)
//
#include <hip/hip_runtime.h>

// LateInteractionScorer: scores[b] = sum_q max_d ( Q[b,q,:]·D[b,d,:] + (1-mask[b,d])*NEG )
// B=64, Q=32, D=4096, H=128, fp32 inputs, fp32 out[64].
// Strategy: bf16 MFMA (16x16x32), streaming HBM-bound. See round journal.

#define BATCH 64
#define QLEN 32
#define DLEN 4096
#define HDIM 128
#define NEGV (-1e30f)

#define WGS_PER_BATCH 8
#define DOCS_PER_WG (DLEN / WGS_PER_BATCH)   // 512
#define DOCS_PER_WAVE (DOCS_PER_WG / 4)      // 128
#define QPAD 136                              // 128 + 8 bf16 pad: row stride 272B -> 2-way bank alias (free)

typedef __attribute__((ext_vector_type(8))) short short8;   // 8 bf16 in 4 VGPRs (MFMA A/B frag)
typedef __attribute__((ext_vector_type(4))) float floatx4;  // MFMA C/D frag

__device__ __forceinline__ unsigned short f2bf(float f) {
    // round-to-nearest-even fp32 -> bf16 (inputs are finite normals; no NaN path needed)
    unsigned u = __float_as_uint(f);
    u += 0x7FFFu + ((u >> 16) & 1u);
    return (unsigned short)(u >> 16);
}

// monotone float -> uint encoding so unsigned atomicMax == float max; enc(x) > 0 for all finite x,
// so memset(0) acts as the -inf sentinel.
__device__ __forceinline__ unsigned encf(float x) {
    unsigned u = __float_as_uint(x);
    return (u & 0x80000000u) ? ~u : (u | 0x80000000u);
}
__device__ __forceinline__ float decf(unsigned u) {
    return (u & 0x80000000u) ? __uint_as_float(u & 0x7FFFFFFFu) : __uint_as_float(~u);
}

__global__ __launch_bounds__(256, 2)
void li_main(const float* __restrict__ qv, const float* __restrict__ dv,
             const int* __restrict__ mask, unsigned* __restrict__ pmax) {
    __shared__ __align__(16) unsigned short qlds[QLEN * QPAD];

    const int b    = blockIdx.x >> 3;          // 8 WGs per batch
    const int blk  = blockIdx.x & 7;
    const int tid  = threadIdx.x;
    const int wave = tid >> 6;
    const int lane = tid & 63;
    const int col  = lane & 15;                // MFMA n / C col index
    const int quad = lane >> 4;                // MFMA k-quad / C row group

    // ---- stage Q[b] (32x128 fp32) -> bf16 LDS, row stride QPAD ----
    {
        const int r = tid >> 3;                // 32 rows
        const int c = (tid & 7) * 16;          // 8 chunks of 16 floats
        const float* src = qv + ((size_t)b * QLEN + r) * HDIM + c;
        unsigned short t[16];
        #pragma unroll
        for (int i = 0; i < 16; ++i) t[i] = f2bf(src[i]);
        unsigned w[8];
        #pragma unroll
        for (int i = 0; i < 8; ++i) w[i] = (unsigned)t[2 * i] | ((unsigned)t[2 * i + 1] << 16);
        uint4 lo = make_uint4(w[0], w[1], w[2], w[3]);
        uint4 hi = make_uint4(w[4], w[5], w[6], w[7]);
        *(uint4*)&qlds[r * QPAD + c]     = lo;
        *(uint4*)&qlds[r * QPAD + c + 8] = hi;
    }
    __syncthreads();

    // ---- hoist A fragments (both q-tiles, all 4 k-chunks) into registers ----
    // A layout: A[m = lane&15][k = quad*8 + j]
    short8 a0[4], a1[4];
    #pragma unroll
    for (int kc = 0; kc < 4; ++kc) {
        a0[kc] = *(const short8*)&qlds[col * QPAD        + kc * 32 + quad * 8];
        a1[kc] = *(const short8*)&qlds[(16 + col) * QPAD + kc * 32 + quad * 8];
    }

    const int dbase0 = blk * DOCS_PER_WG + wave * DOCS_PER_WAVE;
    const float* dbatch = dv + (size_t)b * DLEN * HDIM;
    const int* mrow = mask + b * DLEN;

    float m0[4] = {-3e38f, -3e38f, -3e38f, -3e38f};
    float m1[4] = {-3e38f, -3e38f, -3e38f, -3e38f};

    // ---- doc loop: 8 tiles of 16 docs per wave ----
    #pragma unroll 2
    for (int t = 0; t < 8; ++t) {
        const int d = dbase0 + t * 16 + col;
        const float* dp = dbatch + (size_t)d * HDIM + quad * 8;
        const int mv = mrow[d];
        floatx4 c0 = {0.f, 0.f, 0.f, 0.f};
        floatx4 c1 = {0.f, 0.f, 0.f, 0.f};
        #pragma unroll
        for (int kc = 0; kc < 4; ++kc) {
            // B layout: B[n = lane&15][k = quad*8 + j]; doc rows are [d][k] row-major -> direct
            float4 v0 = *(const float4*)(dp + kc * 32);
            float4 v1 = *(const float4*)(dp + kc * 32 + 4);
            short8 bf;
            bf[0] = (short)f2bf(v0.x); bf[1] = (short)f2bf(v0.y);
            bf[2] = (short)f2bf(v0.z); bf[3] = (short)f2bf(v0.w);
            bf[4] = (short)f2bf(v1.x); bf[5] = (short)f2bf(v1.y);
            bf[6] = (short)f2bf(v1.z); bf[7] = (short)f2bf(v1.w);
            c0 = __builtin_amdgcn_mfma_f32_16x16x32_bf16(a0[kc], bf, c0, 0, 0, 0);
            c1 = __builtin_amdgcn_mfma_f32_16x16x32_bf16(a1[kc], bf, c1, 0, 0, 0);
        }
        // C layout: row q = quad*4 + r (+16 for tile 1), col doc = lane&15
        const float pen = mv ? 0.0f : NEGV;
        #pragma unroll
        for (int r = 0; r < 4; ++r) {
            m0[r] = fmaxf(m0[r], c0[r] + pen);
            m1[r] = fmaxf(m1[r], c1[r] + pen);
        }
    }

    // ---- max-reduce over the 16 doc columns (lane bits 0..3) ----
    #pragma unroll
    for (int off = 1; off < 16; off <<= 1) {
        #pragma unroll
        for (int r = 0; r < 4; ++r) {
            m0[r] = fmaxf(m0[r], __shfl_xor(m0[r], off));
            m1[r] = fmaxf(m1[r], __shfl_xor(m1[r], off));
        }
    }

    if (col == 0) {
        #pragma unroll
        for (int r = 0; r < 4; ++r) {
            atomicMax(&pmax[b * QLEN + quad * 4 + r],      encf(m0[r]));
            atomicMax(&pmax[b * QLEN + 16 + quad * 4 + r], encf(m1[r]));
        }
    }
}

__global__ void li_final(const unsigned* __restrict__ pmax, float* __restrict__ out) {
    const int b = blockIdx.x;
    const int lane = threadIdx.x;  // block of 64, only lanes 0..31 carry data
    float v = (lane < QLEN) ? decf(pmax[b * QLEN + lane]) : 0.0f;
    #pragma unroll
    for (int off = 1; off < 32; off <<= 1) v += __shfl_xor(v, off);
    if (lane == 0) out[b] = v;
}

extern "C" void kernel_launch(void* const* d_in, const int* in_sizes, int n_in,
                              void* d_out, int out_size, void* d_ws, size_t ws_size,
                              hipStream_t stream) {
    const float* qv   = (const float*)d_in[0];
    const float* dv   = (const float*)d_in[1];
    const int*   mask = (const int*)d_in[2];
    unsigned* pmax = (unsigned*)d_ws;          // BATCH*QLEN = 2048 u32 = 8 KB
    float* out = (float*)d_out;

    hipMemsetAsync(pmax, 0, BATCH * QLEN * sizeof(unsigned), stream);  // enc(-inf) sentinel
    li_main<<<dim3(BATCH * WGS_PER_BATCH), dim3(256), 0, stream>>>(qv, dv, mask, pmax);
    li_final<<<dim3(BATCH), dim3(64), 0, stream>>>(pmax, out);
}